// Round 6
// baseline (154.390 us; speedup 1.0000x reference)
//
#include <hip/hip_runtime.h>
#include <hip/hip_bf16.h>

#define NV 100000
#define ND 64
#define NB 4096
#define NL 200
#define MT 13        // m-tiles of 16 rows -> 208 (200 real + 8 zero pad)

typedef __bf16 bf16_t;
typedef __bf16 bf16x8 __attribute__((ext_vector_type(8)));
typedef __bf16 bf16x4 __attribute__((ext_vector_type(4)));
typedef float f32x4 __attribute__((ext_vector_type(4)));

#define TB_ELEMS ((long)NV * ND)      // bf16 shadow emb table elems (12.8 MB)
#define TBV (TB_ELEMS / 8)            // 800000 vector cvt tasks
#define FT1 (128 * 192)               // fW1T elems (B-frag layout [n][k])
#define FT2 (64 * 128)                // fW2T elems
#define CVT_TASKS (TBV + FT1 + FT2)

// ---- kernel 0: f32->bf16 emb table + transposed bf16 MLP weights ----
__global__ __launch_bounds__(256)
void cvt_kernel(const float* __restrict__ emb,
                const float* __restrict__ fW1,
                const float* __restrict__ fW2,
                bf16_t* __restrict__ tb,
                bf16_t* __restrict__ fW1T,
                bf16_t* __restrict__ fW2T)
{
    long t = (long)blockIdx.x * 256 + threadIdx.x;
    if (t >= CVT_TASKS) return;
    if (t < TBV) {
        long i = t * 8;
        f32x4 a0 = *(const f32x4*)(emb + i);
        f32x4 a1 = *(const f32x4*)(emb + i + 4);
        bf16x8 o;
#pragma unroll
        for (int j = 0; j < 4; ++j) { o[j] = (bf16_t)a0[j]; o[j + 4] = (bf16_t)a1[j]; }
        *(bf16x8*)(tb + i) = o;
    } else {
        int u = (int)(t - TBV);
        if (u < FT1) {                     // fW1T[n][k] = fW1[k][n]
            int n = u / 192, k = u - n * 192;
            fW1T[u] = (bf16_t)fW1[k * 128 + n];
        } else {                           // fW2T[n][k] = fW2[k][n]
            int u2 = u - FT1;
            int n = u2 >> 7, k = u2 & 127;
            fW2T[u2] = (bf16_t)fW2[k * 64 + n];
        }
    }
}

// Fused DIN, 1 batch row / 256-thread block (4 blocks/CU, LDS 38 KB).
//  - round-2's block shape (4 independent blocks/CU beat 2x512 lockstep)
//  - phase 2: coalesced f32 aW1 reads (round-5's strided awT reverted)
//  - MFMA MLP head with register-prefetched transposed bf16 weights
//  - biases in MFMA C-init; one-pass softmax; vectorized pooling
// histA/wbT: 16B-granular XOR swizzle (elem ^= (row&7)<<3), both sides.
__global__ __launch_bounds__(256, 4)
void din_kernel1(const int* __restrict__ item_ids,
                 const int* __restrict__ history,
                 const int* __restrict__ hist_len,
                 const float* __restrict__ emb,
                 const bf16_t* __restrict__ tb,
                 const float* __restrict__ aW1,
                 const float* __restrict__ ab1,
                 const float* __restrict__ aW2,
                 const bf16_t* __restrict__ fW1T, const float* __restrict__ fb1,
                 const bf16_t* __restrict__ fW2T, const float* __restrict__ fb2,
                 const float* __restrict__ fW3, const float* __restrict__ fb3,
                 float* __restrict__ out)
{
    __shared__ __align__(16) bf16_t histA[208 * 64];   // 26624 B
    __shared__ __align__(16) bf16_t wbT[64 * 64];      // 8192 B, wbT[n][k]
    __shared__ float tgt[64];
    __shared__ __align__(16) float scores[208];
    __shared__ float wts[208];
    __shared__ float pp[4 * 64];
    __shared__ float red[8];
    __shared__ float cb2[64];

    // MLP tiles alias histA (dead after pooling phase)
    bf16_t* comb16 = histA;                          // [16][200] bf16
    bf16_t* z1s    = histA + 3328;                   // [16][136] bf16
    float*  z2f    = (float*)(histA + 5504);         // [64] f32

    const int b   = blockIdx.x;
    const int tid = threadIdx.x;
    const int len = hist_len[b];

    if (tid < 64) tgt[tid] = emb[(long)item_ids[b] * ND + tid];

    // ---- phase 1: gather 208 rows from bf16 table (all loads first) ----
    {
        const int p  = tid & 1;       // half-row: 32 bf16 = 64 B
        const int l0 = tid >> 1;      // 0..127
        const int l1 = l0 + 128;      // 128..255 (stores clipped at 208)
        const bf16x8 z = (bf16x8)(bf16_t)0.f;
        bf16x8 a0 = z, a1 = z, a2 = z, a3 = z;
        bf16x8 c0 = z, c1 = z, c2 = z, c3 = z;
        if (l0 < len) {
            const bf16_t* s = tb + (long)history[(long)b * NL + l0] * ND + p * 32;
            a0 = *(const bf16x8*)(s);
            a1 = *(const bf16x8*)(s + 8);
            a2 = *(const bf16x8*)(s + 16);
            a3 = *(const bf16x8*)(s + 24);
        }
        if (l1 < len) {
            const bf16_t* s = tb + (long)history[(long)b * NL + l1] * ND + p * 32;
            c0 = *(const bf16x8*)(s);
            c1 = *(const bf16x8*)(s + 8);
            c2 = *(const bf16x8*)(s + 16);
            c3 = *(const bf16x8*)(s + 24);
        }
        {
            bf16_t* d = &histA[l0 * 64];
            const int S = (l0 & 7) << 3;
            *(bf16x8*)&d[(p * 32 +  0) ^ S] = a0;
            *(bf16x8*)&d[(p * 32 +  8) ^ S] = a1;
            *(bf16x8*)&d[(p * 32 + 16) ^ S] = a2;
            *(bf16x8*)&d[(p * 32 + 24) ^ S] = a3;
        }
        if (l1 < 208) {
            bf16_t* d = &histA[l1 * 64];
            const int S = (l1 & 7) << 3;
            *(bf16x8*)&d[(p * 32 +  0) ^ S] = c0;
            *(bf16x8*)&d[(p * 32 +  8) ^ S] = c1;
            *(bf16x8*)&d[(p * 32 + 16) ^ S] = c2;
            *(bf16x8*)&d[(p * 32 + 24) ^ S] = c3;
        }
    }

    // ---- phase 2: Wb^T from one coalesced pass over f32 aW1 ----
    {
        const int n  = tid & 63;
        const int kp = tid >> 6;      // 0..3 -> k = kp*16 + i
        const long t0 = (long)item_ids[b] * ND;
        f32x4 tka = *(const f32x4*)(emb + t0 + kp * 16);
        f32x4 tkb = *(const f32x4*)(emb + t0 + kp * 16 + 4);
        f32x4 tkc = *(const f32x4*)(emb + t0 + kp * 16 + 8);
        f32x4 tkd = *(const f32x4*)(emb + t0 + kp * 16 + 12);
        float csum = 0.f;
        bf16x8 w0v, w1v;
#pragma unroll
        for (int i = 0; i < 16; ++i) {
            int k = kp * 16 + i;
            float tk = (i < 4) ? tka[i] : (i < 8) ? tkb[i - 4]
                     : (i < 12) ? tkc[i - 8] : tkd[i - 12];
            float ah = aW1[k * 64 + n];
            float am = aW1[(64 + k) * 64 + n];
            float ap = aW1[(128 + k) * 64 + n];
            float w  = ah + tk * ap;
            if (i < 8) w0v[i] = (bf16_t)w; else w1v[i - 8] = (bf16_t)w;
            csum += tk * am;
        }
        const int S = (n & 7) << 3;
        *(bf16x8*)&wbT[n * 64 + ((kp * 16    ) ^ S)] = w0v;
        *(bf16x8*)&wbT[n * 64 + ((kp * 16 + 8) ^ S)] = w1v;
        pp[kp * 64 + n] = csum;
    }
    __syncthreads();   // B1

    if (tid < 64)
        cb2[tid] = ab1[tid] + pp[tid] + pp[64 + tid] + pp[128 + tid] + pp[192 + tid];
    __syncthreads();   // B2

    // ---- phase 3: S^T = Wb^T @ hist^T via MFMA (bias in C-init) ----
    {
        const int wave = tid >> 6;
        const int lane = tid & 63;
        const int col  = lane & 15;
        const int quad = lane >> 4;

        bf16x8 afrag[4][2];
#pragma unroll
        for (int nt = 0; nt < 4; ++nt) {
            const int n = nt * 16 + col;
            const int S = (n & 7) << 3;
#pragma unroll
            for (int kb = 0; kb < 2; ++kb)
                afrag[nt][kb] = *(const bf16x8*)&wbT[n * 64 + ((kb * 32 + quad * 8) ^ S)];
        }
        float cv[4][4], a2[4][4];
#pragma unroll
        for (int nt = 0; nt < 4; ++nt)
#pragma unroll
            for (int i = 0; i < 4; ++i) {
                const int no = nt * 16 + quad * 4 + i;
                cv[nt][i] = cb2[no];
                a2[nt][i] = aW2[no];
            }

        for (int mt = wave; mt < MT; mt += 4) {
            const int l = mt * 16 + col;     // B-operand n = l
            const int S = (l & 7) << 3;
            const bf16_t* base = &histA[l * 64];
            bf16x8 bf0 = *(const bf16x8*)&base[(     quad * 8) ^ S];
            bf16x8 bf1 = *(const bf16x8*)&base[(32 + quad * 8) ^ S];
            float sc = 0.f;
#pragma unroll
            for (int nt = 0; nt < 4; ++nt) {
                f32x4 acc = {cv[nt][0], cv[nt][1], cv[nt][2], cv[nt][3]};
                acc = __builtin_amdgcn_mfma_f32_16x16x32_bf16(afrag[nt][0], bf0, acc, 0, 0, 0);
                acc = __builtin_amdgcn_mfma_f32_16x16x32_bf16(afrag[nt][1], bf1, acc, 0, 0, 0);
#pragma unroll
                for (int i = 0; i < 4; ++i) {
                    float h = acc[i] > 0.f ? acc[i] : 0.f;
                    sc += h * a2[nt][i];
                }
            }
            sc += __shfl_xor(sc, 16, 64);
            sc += __shfl_xor(sc, 32, 64);
            if (quad == 0) scores[mt * 16 + col] = sc;
        }
    }
    __syncthreads();   // B3

    // ---- phase 4: one-pass softmax (wave-local e; publish m_w, s_w) ----
    {
        float s = (tid < NL) ? scores[tid] : -1e30f;
        float m = s;
        for (int off = 32; off > 0; off >>= 1) m = fmaxf(m, __shfl_xor(m, off, 64));
        float e = (tid < NL) ? __expf(s - m) : 0.f;   // local to wave max
        if (tid < NL) wts[tid] = e;
        else if (tid < 208) wts[tid] = 0.f;           // zero pad for phase 5
        float ss = e;
        for (int off = 32; off > 0; off >>= 1) ss += __shfl_xor(ss, off, 64);
        if ((tid & 63) == 0) { red[tid >> 6] = m; red[4 + (tid >> 6)] = ss; }
    }
    __syncthreads();   // B4

    // ---- phase 5: pooled partials; rescale by exp(m_w-m)*rtot inline ----
    // l = g + 16j with g<16  =>  l>>6 == j>>2 (compile-time scale select)
    {
        const int c  = tid & 15;      // d = c*4 .. c*4+3
        const int g  = tid >> 4;      // 0..15 row-groups
        const int w4 = tid >> 6;
        const float m0 = red[0], m1 = red[1], m2 = red[2], m3 = red[3];
        const float mg = fmaxf(fmaxf(m0, m1), fmaxf(m2, m3));
        float sc0 = __expf(m0 - mg), sc1 = __expf(m1 - mg);
        float sc2 = __expf(m2 - mg), sc3 = __expf(m3 - mg);
        const float rtot = 1.f / (sc0 * red[4] + sc1 * red[5] +
                                  sc2 * red[6] + sc3 * red[7]);
        sc0 *= rtot; sc1 *= rtot; sc2 *= rtot; sc3 *= rtot;
        f32x4 acc = {0.f, 0.f, 0.f, 0.f};
#pragma unroll
        for (int j = 0; j < 13; ++j) {
            const int l = g + j * 16;
            const float scj = (j < 4) ? sc0 : (j < 8) ? sc1 : (j < 12) ? sc2 : sc3;
            const float wl = wts[l] * scj;
            bf16x4 v = *(const bf16x4*)&histA[l * 64 + ((c * 4) ^ ((l & 7) << 3))];
#pragma unroll
            for (int k = 0; k < 4; ++k) acc[k] += wl * (float)v[k];
        }
#pragma unroll
        for (int k = 0; k < 4; ++k) {
            acc[k] += __shfl_xor(acc[k], 16, 64);
            acc[k] += __shfl_xor(acc[k], 32, 64);
        }
        if ((tid & 63) < 16) *(f32x4*)&pp[w4 * 64 + c * 4] = acc;
    }

    // prefetch MLP weights to registers (global, L2-hot; no LDS deps)
    bf16x8 bw1[2][6]; float b1v[2];
    bf16x8 bw2[4];    float b2v;
    {
        const int wave = tid >> 6, lane = tid & 63;
        const int col = lane & 15, quad = lane >> 4;
#pragma unroll
        for (int tt = 0; tt < 2; ++tt) {
            const int n = (wave * 2 + tt) * 16 + col;     // 0..127
#pragma unroll
            for (int ks = 0; ks < 6; ++ks)
                bw1[tt][ks] = *(const bf16x8*)&fW1T[(long)n * 192 + ks * 32 + quad * 8];
            b1v[tt] = fb1[n];
        }
        const int n2 = wave * 16 + col;                   // 0..63
#pragma unroll
        for (int ks = 0; ks < 4; ++ks)
            bw2[ks] = *(const bf16x8*)&fW2T[(long)n2 * 128 + ks * 32 + quad * 8];
        b2v = fb2[n2];
    }
    __syncthreads();   // B5 (histA dead; aliases go live)

    // ---- phase 6: comb16 tile (row 0 = comb; rows 1-15 zero) ----
    {
        if (tid < 192) {
            const int d = tid & 63;
            float v;
            if (tid < 64) v = tgt[d];
            else {
                float pl = pp[d] + pp[64 + d] + pp[128 + d] + pp[192 + d];
                v = (tid < 128) ? pl : pl - tgt[d];
            }
            comb16[tid] = (bf16_t)v;
        }
        // zero rows 1..15, cols 0..191 (cols 192..199 never read by MFMA)
        const bf16x8 z = (bf16x8)(bf16_t)0.f;
        for (int s = tid; s < 360; s += 256) {
            const int m = s / 24 + 1;
            const int c = (s % 24) * 8;
            *(bf16x8*)&comb16[m * 200 + c] = z;
        }
    }
    __syncthreads();   // B6

    // ---- phase 7: z1 = relu(comb @ fW1 + fb1) via MFMA [192->128] ----
    {
        const int wave = tid >> 6, lane = tid & 63;
        const int col = lane & 15, quad = lane >> 4;
#pragma unroll
        for (int tt = 0; tt < 2; ++tt) {
            f32x4 acc = {b1v[tt], b1v[tt], b1v[tt], b1v[tt]};
#pragma unroll
            for (int ks = 0; ks < 6; ++ks) {
                bf16x8 a = *(const bf16x8*)&comb16[col * 200 + ks * 32 + quad * 8];
                acc = __builtin_amdgcn_mfma_f32_16x16x32_bf16(a, bw1[tt][ks], acc, 0, 0, 0);
            }
            const int n = (wave * 2 + tt) * 16 + col;
#pragma unroll
            for (int i = 0; i < 4; ++i) {
                const int m = quad * 4 + i;
                float zv = (m == 0) ? fmaxf(acc[i], 0.f) : 0.f;
                z1s[m * 136 + n] = (bf16_t)zv;
            }
        }
    }
    __syncthreads();   // B7

    // ---- phase 8: z2 = relu(z1 @ fW2 + fb2) via MFMA [128->64] ----
    {
        const int wave = tid >> 6, lane = tid & 63;
        const int col = lane & 15, quad = lane >> 4;
        f32x4 acc = {b2v, b2v, b2v, b2v};
#pragma unroll
        for (int ks = 0; ks < 4; ++ks) {
            bf16x8 a = *(const bf16x8*)&z1s[col * 136 + ks * 32 + quad * 8];
            acc = __builtin_amdgcn_mfma_f32_16x16x32_bf16(a, bw2[ks], acc, 0, 0, 0);
        }
        const int n2 = wave * 16 + col;
        if (quad == 0) z2f[n2] = fmaxf(acc[0], 0.f);   // m = 0 row only
    }
    __syncthreads();   // B8

    // ---- phase 9: out = sigmoid(z2 . fW3 + fb3) ----
    if (tid < 64) {
        float s = z2f[tid] * fW3[tid];
        for (int off = 32; off > 0; off >>= 1) s += __shfl_xor(s, off, 64);
        if (tid == 0) out[b] = 1.f / (1.f + __expf(-(s + fb3[0])));
    }
}

extern "C" void kernel_launch(void* const* d_in, const int* in_sizes, int n_in,
                              void* d_out, int out_size, void* d_ws, size_t ws_size,
                              hipStream_t stream) {
    const int*   item_ids = (const int*)d_in[0];
    const int*   history  = (const int*)d_in[1];
    const int*   hist_len = (const int*)d_in[2];
    const float* emb      = (const float*)d_in[3];
    const float* aW1      = (const float*)d_in[4];
    const float* ab1      = (const float*)d_in[5];
    const float* aW2      = (const float*)d_in[6];
    // d_in[7] = ab2: softmax is shift-invariant, exactly cancels -> unused
    const float* fW1      = (const float*)d_in[8];
    const float* fb1      = (const float*)d_in[9];
    const float* fW2      = (const float*)d_in[10];
    const float* fb2      = (const float*)d_in[11];
    const float* fW3      = (const float*)d_in[12];
    const float* fb3      = (const float*)d_in[13];

    // ws layout: bf16 [emb table | fW1T | fW2T], contiguous, 16B-aligned
    bf16_t* tb   = (bf16_t*)d_ws;
    bf16_t* fW1T = tb + TB_ELEMS;
    bf16_t* fW2T = fW1T + FT1;

    cvt_kernel<<<(int)((CVT_TASKS + 255) / 256), 256, 0, stream>>>(emb, fW1, fW2,
                                                                   tb, fW1T, fW2T);
    din_kernel1<<<NB, 256, 0, stream>>>(item_ids, history, hist_len, emb, tb,
                                        aW1, ab1, aW2,
                                        fW1T, fb1, fW2T, fb2, fW3, fb3,
                                        (float*)d_out);
}

// Round 7
// 141.751 us; speedup vs baseline: 1.0892x; 1.0892x over previous
//
#include <hip/hip_runtime.h>
#include <hip/hip_bf16.h>

#define NV 100000
#define ND 64
#define NB 4096
#define NL 200
#define MT 13        // m-tiles of 16 rows -> 208 (200 real + 8 zero pad)

typedef __bf16 bf16_t;
typedef __bf16 bf16x8 __attribute__((ext_vector_type(8)));
typedef __bf16 bf16x4 __attribute__((ext_vector_type(4)));
typedef float f32x4 __attribute__((ext_vector_type(4)));

#define TB_ELEMS ((long)NV * ND)      // bf16 shadow emb table elems (12.8 MB)
#define TBV (TB_ELEMS / 8)            // 800000 vector cvt tasks
#define FT1 (128 * 192)               // fW1T elems (B-frag layout [n][k])
#define FT2 (64 * 128)                // fW2T elems
#define AWB (192 * 64)                // awB: aW1 cast to bf16, same [k][n] layout
#define CVT_TASKS (TBV + FT1 + FT2 + AWB)

// ---- kernel 0: f32->bf16 emb table + MLP weights (transposed) + aW1 ----
__global__ __launch_bounds__(256)
void cvt_kernel(const float* __restrict__ emb,
                const float* __restrict__ aW1,
                const float* __restrict__ fW1,
                const float* __restrict__ fW2,
                bf16_t* __restrict__ tb,
                bf16_t* __restrict__ fW1T,
                bf16_t* __restrict__ fW2T,
                bf16_t* __restrict__ awB)
{
    long t = (long)blockIdx.x * 256 + threadIdx.x;
    if (t >= CVT_TASKS) return;
    if (t < TBV) {
        long i = t * 8;
        f32x4 a0 = *(const f32x4*)(emb + i);
        f32x4 a1 = *(const f32x4*)(emb + i + 4);
        bf16x8 o;
#pragma unroll
        for (int j = 0; j < 4; ++j) { o[j] = (bf16_t)a0[j]; o[j + 4] = (bf16_t)a1[j]; }
        *(bf16x8*)(tb + i) = o;
    } else {
        int u = (int)(t - TBV);
        if (u < FT1) {                     // fW1T[n][k] = fW1[k][n]
            int n = u / 192, k = u - n * 192;
            fW1T[u] = (bf16_t)fW1[k * 128 + n];
        } else if (u < FT1 + FT2) {        // fW2T[n][k] = fW2[k][n]
            int u2 = u - FT1;
            int n = u2 >> 7, k = u2 & 127;
            fW2T[u2] = (bf16_t)fW2[k * 64 + n];
        } else {                           // awB = bf16(aW1), same layout
            int u3 = u - FT1 - FT2;
            awB[u3] = (bf16_t)aW1[u3];
        }
    }
}

// Fused DIN, 2 batch rows / block (512 thr) — R4 structure consolidated:
//  - phase 2: per-wave (n,kq) mapping -> csum via 2 shfl, cb2 direct
//    (no pp reduce, one less barrier); ah/ap read as bf16 (same layout)
//  - one-pass softmax; MFMA MLP; no zero-fill of garbage MFMA rows
//  - 7 barriers (R4 had 9)
// LDS 76 KB -> 2 blocks/CU.
__global__ __launch_bounds__(512, 4)
void din_kernel1(const int* __restrict__ item_ids,
                 const int* __restrict__ history,
                 const int* __restrict__ hist_len,
                 const float* __restrict__ emb,
                 const bf16_t* __restrict__ tb,
                 const float* __restrict__ aW1,
                 const bf16_t* __restrict__ awB,
                 const float* __restrict__ ab1,
                 const float* __restrict__ aW2,
                 const bf16_t* __restrict__ fW1T, const float* __restrict__ fb1,
                 const bf16_t* __restrict__ fW2T, const float* __restrict__ fb2,
                 const float* __restrict__ fW3, const float* __restrict__ fb3,
                 float* __restrict__ out)
{
    __shared__ __align__(16) bf16_t histA[2][208 * 64];   // 53248 B
    __shared__ __align__(16) bf16_t wbT[2][64 * 64];      // 16384 B, wbT[n][k]
    __shared__ float tgt[2][64];
    __shared__ __align__(16) float scores[2][208];
    __shared__ float wts[2][208];
    __shared__ float pp2[2][256];
    __shared__ float red[2][8];
    __shared__ float cb2[2][64];

    // MLP tiles alias wbT (dead after phase 3)
    bf16_t* comb16 = (bf16_t*)wbT;                  // [16][200] bf16, 6400 B
    bf16_t* z1s    = (bf16_t*)wbT + 3200;           // [16][136] bf16, 4352 B
    float*  z2f    = (float*)((bf16_t*)wbT + 5376); // [2][64] f32,    512 B

    const int b0  = blockIdx.x * 2;
    const int tid = threadIdx.x;
    const int len0 = hist_len[b0];
    const int len1 = hist_len[b0 + 1];

    if (tid < 128) {
        int bx = tid >> 6, d = tid & 63;
        tgt[bx][d] = emb[(long)item_ids[b0 + bx] * ND + d];
    }

    // ---- phase 1: gather 2x208 rows from bf16 table (all loads first) ----
    {
        const int p = tid & 1;        // half-row: 32 bf16 = 64 B
        const int s = tid >> 1;       // 0..255
        const int bxA = (s >= 208);
        const int lA  = s - bxA * 208;
        const int lB  = s + 48;
        const int lenA = bxA ? len1 : len0;
        const bool vB = (s < 160);
        const bf16x8 z = (bf16x8)(bf16_t)0.f;
        bf16x8 a0 = z, a1 = z, a2 = z, a3 = z;
        bf16x8 c0 = z, c1 = z, c2 = z, c3 = z;
        if (lA < lenA) {
            const bf16_t* src = tb + (long)history[(long)(b0 + bxA) * NL + lA] * ND + p * 32;
            a0 = *(const bf16x8*)(src);
            a1 = *(const bf16x8*)(src + 8);
            a2 = *(const bf16x8*)(src + 16);
            a3 = *(const bf16x8*)(src + 24);
        }
        if (vB && lB < len1) {
            const bf16_t* src = tb + (long)history[(long)(b0 + 1) * NL + lB] * ND + p * 32;
            c0 = *(const bf16x8*)(src);
            c1 = *(const bf16x8*)(src + 8);
            c2 = *(const bf16x8*)(src + 16);
            c3 = *(const bf16x8*)(src + 24);
        }
        {
            bf16_t* d = &histA[bxA][lA * 64];
            const int S = (lA & 7) << 3;
            *(bf16x8*)&d[(p * 32 +  0) ^ S] = a0;
            *(bf16x8*)&d[(p * 32 +  8) ^ S] = a1;
            *(bf16x8*)&d[(p * 32 + 16) ^ S] = a2;
            *(bf16x8*)&d[(p * 32 + 24) ^ S] = a3;
        }
        if (vB) {
            bf16_t* d = &histA[1][lB * 64];
            const int S = (lB & 7) << 3;
            *(bf16x8*)&d[(p * 32 +  0) ^ S] = c0;
            *(bf16x8*)&d[(p * 32 +  8) ^ S] = c1;
            *(bf16x8*)&d[(p * 32 + 16) ^ S] = c2;
            *(bf16x8*)&d[(p * 32 + 24) ^ S] = c3;
        }
    }

    // ---- phase 2: Wb^T + cb2, csum reduced in-wave (no extra barrier) ----
    // wave w: bx = w&1, n in [(w>>1)*16, +16); lane: kq = lane>>4 covers
    // k = kq*16..+16. csum for column n lives in 4 lanes of ONE wave.
    {
        const int lane = tid & 63;
        const int w    = tid >> 6;
        const int bx   = w & 1;
        const int n    = ((w >> 1) << 4) | (lane & 15);
        const int kq   = lane >> 4;                   // 0..3
        const long t0  = (long)item_ids[b0 + bx] * ND;
        f32x4 tka = *(const f32x4*)(emb + t0 + kq * 16);
        f32x4 tkb = *(const f32x4*)(emb + t0 + kq * 16 + 4);
        f32x4 tkc = *(const f32x4*)(emb + t0 + kq * 16 + 8);
        f32x4 tkd = *(const f32x4*)(emb + t0 + kq * 16 + 12);
        float csum = 0.f;
        bf16x8 w0v, w1v;
#pragma unroll
        for (int i = 0; i < 16; ++i) {
            int k = kq * 16 + i;
            float tk = (i < 4) ? tka[i] : (i < 8) ? tkb[i - 4]
                     : (i < 12) ? tkc[i - 8] : tkd[i - 12];
            float ah = (float)awB[k * 64 + n];
            float am = aW1[(64 + k) * 64 + n];
            float ap = (float)awB[(128 + k) * 64 + n];
            float wv = ah + tk * ap;
            if (i < 8) w0v[i] = (bf16_t)wv; else w1v[i - 8] = (bf16_t)wv;
            csum += tk * am;
        }
        const int S = (n & 7) << 3;
        *(bf16x8*)&wbT[bx][n * 64 + ((kq * 16    ) ^ S)] = w0v;
        *(bf16x8*)&wbT[bx][n * 64 + ((kq * 16 + 8) ^ S)] = w1v;
        csum += __shfl_xor(csum, 16, 64);
        csum += __shfl_xor(csum, 32, 64);
        if (kq == 0) cb2[bx][n] = ab1[n] + csum;
    }
    __syncthreads();   // B1

    // ---- phase 3: S^T = Wb^T @ hist^T via MFMA (bias in C-init) ----
    {
        const int wave = tid >> 6;
        const int lane = tid & 63;
        const int bx   = wave & 1;
        const int col  = lane & 15;
        const int quad = lane >> 4;

        bf16x8 afrag[4][2];
#pragma unroll
        for (int nt = 0; nt < 4; ++nt) {
            const int n = nt * 16 + col;
            const int S = (n & 7) << 3;
#pragma unroll
            for (int kb = 0; kb < 2; ++kb)
                afrag[nt][kb] = *(const bf16x8*)&wbT[bx][n * 64 + ((kb * 32 + quad * 8) ^ S)];
        }
        float cv[4][4], a2[4][4];
#pragma unroll
        for (int nt = 0; nt < 4; ++nt)
#pragma unroll
            for (int i = 0; i < 4; ++i) {
                const int no = nt * 16 + quad * 4 + i;
                cv[nt][i] = cb2[bx][no];
                a2[nt][i] = aW2[no];
            }

        for (int mt = (wave >> 1); mt < MT; mt += 4) {
            const int l = mt * 16 + col;     // B-operand n = l
            const int S = (l & 7) << 3;
            const bf16_t* base = &histA[bx][l * 64];
            bf16x8 bf0 = *(const bf16x8*)&base[(     quad * 8) ^ S];
            bf16x8 bf1 = *(const bf16x8*)&base[(32 + quad * 8) ^ S];
            float sc = 0.f;
#pragma unroll
            for (int nt = 0; nt < 4; ++nt) {
                f32x4 acc = {cv[nt][0], cv[nt][1], cv[nt][2], cv[nt][3]};
                acc = __builtin_amdgcn_mfma_f32_16x16x32_bf16(afrag[nt][0], bf0, acc, 0, 0, 0);
                acc = __builtin_amdgcn_mfma_f32_16x16x32_bf16(afrag[nt][1], bf1, acc, 0, 0, 0);
#pragma unroll
                for (int i = 0; i < 4; ++i) {
                    float h = acc[i] > 0.f ? acc[i] : 0.f;
                    sc += h * a2[nt][i];
                }
            }
            sc += __shfl_xor(sc, 16, 64);
            sc += __shfl_xor(sc, 32, 64);
            if (quad == 0) scores[bx][mt * 16 + col] = sc;
        }
    }
    __syncthreads();   // B2

    // ---- phase 4: one-pass softmax (wave-local e; publish m_w, s_w) ----
    {
        const int bx = tid >> 8, t = tid & 255;
        float s = (t < NL) ? scores[bx][t] : -1e30f;
        float m = s;
        for (int off = 32; off > 0; off >>= 1) m = fmaxf(m, __shfl_xor(m, off, 64));
        float e = (t < NL) ? __expf(s - m) : 0.f;     // local to wave max
        if (t < NL) wts[bx][t] = e;
        else if (t < 208) wts[bx][t] = 0.f;           // zero pad for phase 5
        float ss = e;
        for (int off = 32; off > 0; off >>= 1) ss += __shfl_xor(ss, off, 64);
        if ((t & 63) == 0) { red[bx][t >> 6] = m; red[bx][4 + (t >> 6)] = ss; }
    }
    __syncthreads();   // B3

    // prefetch MLP weights to registers (global, L2-hot; no LDS deps)
    bf16x8 bw1[6]; float b1v;
    bf16x8 bw2[4]; float b2v = 0.f;
    {
        const int wave = tid >> 6, lane = tid & 63;
        const int col = lane & 15, quad = lane >> 4;
        const int n = wave * 16 + col;          // 0..127
#pragma unroll
        for (int ks = 0; ks < 6; ++ks)
            bw1[ks] = *(const bf16x8*)&fW1T[(long)n * 192 + ks * 32 + quad * 8];
        b1v = fb1[n];
        if (wave < 4) {
            const int n2 = wave * 16 + col;     // 0..63
#pragma unroll
            for (int ks = 0; ks < 4; ++ks)
                bw2[ks] = *(const bf16x8*)&fW2T[(long)n2 * 128 + ks * 32 + quad * 8];
            b2v = fb2[n2];
        }
    }

    // ---- phase 5: pooled partials; rescale by exp(m_w-m)*rtot inline ----
    // l = g + 16j with g<16  =>  l>>6 == j>>2 (compile-time scale select)
    {
        const int bx = tid >> 8, t = tid & 255;
        const int c = t & 15;         // d = c*4 .. c*4+3
        const int g = t >> 4;         // 0..15 row-groups
        const int w4 = (tid >> 6) & 3;
        const float m0 = red[bx][0], m1 = red[bx][1], m2 = red[bx][2], m3 = red[bx][3];
        const float mg = fmaxf(fmaxf(m0, m1), fmaxf(m2, m3));
        float sc0 = __expf(m0 - mg), sc1 = __expf(m1 - mg);
        float sc2 = __expf(m2 - mg), sc3 = __expf(m3 - mg);
        const float rtot = 1.f / (sc0 * red[bx][4] + sc1 * red[bx][5] +
                                  sc2 * red[bx][6] + sc3 * red[bx][7]);
        sc0 *= rtot; sc1 *= rtot; sc2 *= rtot; sc3 *= rtot;
        f32x4 acc = {0.f, 0.f, 0.f, 0.f};
#pragma unroll
        for (int j = 0; j < 13; ++j) {
            const int l = g + j * 16;
            const float scj = (j < 4) ? sc0 : (j < 8) ? sc1 : (j < 12) ? sc2 : sc3;
            const float wl = wts[bx][l] * scj;
            bf16x4 v = *(const bf16x4*)&histA[bx][l * 64 + ((c * 4) ^ ((l & 7) << 3))];
#pragma unroll
            for (int k = 0; k < 4; ++k) acc[k] += wl * (float)v[k];
        }
#pragma unroll
        for (int k = 0; k < 4; ++k) {
            acc[k] += __shfl_xor(acc[k], 16, 64);
            acc[k] += __shfl_xor(acc[k], 32, 64);
        }
        if ((tid & 63) < 16) *(f32x4*)&pp2[bx][w4 * 64 + c * 4] = acc;
    }
    __syncthreads();   // B4 (wbT dead; aliases go live)

    // ---- phase 6: comb16 rows 0-1 only (rows 2-15 garbage, never observed:
    //      MFMA C-row m depends only on A-row m) ----
    {
        const int bx = tid >> 8, t = tid & 255;
        if (t < 192) {
            const int d = t & 63;
            float v;
            if (t < 64) v = tgt[bx][d];
            else {
                float pl = pp2[bx][d] + pp2[bx][64 + d] + pp2[bx][128 + d] + pp2[bx][192 + d];
                v = (t < 128) ? pl : pl - tgt[bx][d];
            }
            comb16[bx * 200 + t] = (bf16_t)v;
        }
    }
    __syncthreads();   // B5

    // ---- phase 7: z1 = relu(comb @ fW1 + fb1) via MFMA [192->128] ----
    {
        const int wave = tid >> 6, lane = tid & 63;   // wave = nt (8 tiles)
        const int col = lane & 15, quad = lane >> 4;
        f32x4 acc = {b1v, b1v, b1v, b1v};
#pragma unroll
        for (int ks = 0; ks < 6; ++ks) {
            bf16x8 a = *(const bf16x8*)&comb16[col * 200 + ks * 32 + quad * 8];
            acc = __builtin_amdgcn_mfma_f32_16x16x32_bf16(a, bw1[ks], acc, 0, 0, 0);
        }
        const int n = wave * 16 + col;
#pragma unroll
        for (int i = 0; i < 4; ++i) {
            const int m = quad * 4 + i;
            if (m < 2) z1s[m * 136 + n] = (bf16_t)fmaxf(acc[i], 0.f);
        }
    }
    __syncthreads();   // B6

    // ---- phase 8: z2 = relu(z1 @ fW2 + fb2) via MFMA [128->64] ----
    {
        const int wave = tid >> 6, lane = tid & 63;
        const int col = lane & 15, quad = lane >> 4;
        if (wave < 4) {
            f32x4 acc = {b2v, b2v, b2v, b2v};
#pragma unroll
            for (int ks = 0; ks < 4; ++ks) {
                bf16x8 a = *(const bf16x8*)&z1s[col * 136 + ks * 32 + quad * 8];
                acc = __builtin_amdgcn_mfma_f32_16x16x32_bf16(a, bw2[ks], acc, 0, 0, 0);
            }
            const int n2 = wave * 16 + col;
#pragma unroll
            for (int i = 0; i < 4; ++i) {
                const int m = quad * 4 + i;
                if (m < 2) z2f[m * 64 + n2] = fmaxf(acc[i], 0.f);
            }
        }
    }
    __syncthreads();   // B7

    // ---- phase 9: out = sigmoid(z2 . fW3 + fb3) ----
    if (tid < 128) {
        const int bx = tid >> 6, j = tid & 63;
        float s = z2f[bx * 64 + j] * fW3[j];
        for (int off = 32; off > 0; off >>= 1) s += __shfl_xor(s, off, 64);
        if (j == 0) out[b0 + bx] = 1.f / (1.f + __expf(-(s + fb3[0])));
    }
}

extern "C" void kernel_launch(void* const* d_in, const int* in_sizes, int n_in,
                              void* d_out, int out_size, void* d_ws, size_t ws_size,
                              hipStream_t stream) {
    const int*   item_ids = (const int*)d_in[0];
    const int*   history  = (const int*)d_in[1];
    const int*   hist_len = (const int*)d_in[2];
    const float* emb      = (const float*)d_in[3];
    const float* aW1      = (const float*)d_in[4];
    const float* ab1      = (const float*)d_in[5];
    const float* aW2      = (const float*)d_in[6];
    // d_in[7] = ab2: softmax is shift-invariant, exactly cancels -> unused
    const float* fW1      = (const float*)d_in[8];
    const float* fb1      = (const float*)d_in[9];
    const float* fW2      = (const float*)d_in[10];
    const float* fb2      = (const float*)d_in[11];
    const float* fW3      = (const float*)d_in[12];
    const float* fb3      = (const float*)d_in[13];

    // ws layout: bf16 [emb table | fW1T | fW2T | awB], contiguous, 16B-aligned
    bf16_t* tb   = (bf16_t*)d_ws;
    bf16_t* fW1T = tb + TB_ELEMS;
    bf16_t* fW2T = fW1T + FT1;
    bf16_t* awBp = fW2T + FT2;

    cvt_kernel<<<(int)((CVT_TASKS + 255) / 256), 256, 0, stream>>>(
        emb, aW1, fW1, fW2, tb, fW1T, fW2T, awBp);
    din_kernel1<<<NB / 2, 512, 0, stream>>>(item_ids, history, hist_len, emb, tb,
                                            aW1, awBp, ab1, aW2,
                                            fW1T, fb1, fW2T, fb2, fW3, fb3,
                                            (float*)d_out);
}